// Round 11
// baseline (283.107 us; speedup 1.0000x reference)
//
#include <hip/hip_runtime.h>

typedef unsigned int u32;
typedef unsigned short u16;
typedef __bf16 bf16x8 __attribute__((ext_vector_type(8)));
typedef float f32x4 __attribute__((ext_vector_type(4)));
typedef float f32x2 __attribute__((ext_vector_type(2)));

__device__ __forceinline__ u16 f2bf(float f) {
  u32 u = __builtin_bit_cast(u32, f);
  u32 r = (u + 0x7fffu + ((u >> 16) & 1u)) >> 16;   // RTNE
  return (u16)r;
}

// ---------------- fused pre-pass: hist | conv x (bf16 + fp8) | conv W ----------------
// bktTotal must be zeroed (hipMemsetAsync) before this kernel.
__global__ __launch_bounds__(256) void pre_k(const float* __restrict__ x, u16* __restrict__ xbf,
                                             u32* __restrict__ xq,
                                             const float* __restrict__ W, u16* __restrict__ wbf,
                                             const int* __restrict__ dst, int E,
                                             u32* __restrict__ bktTotal, int N, int nbkt,
                                             int nba, int nbx) {
  int b = blockIdx.x, tid = threadIdx.x;
  if (b < nba) {                       // histogram over buckets (dst>>8)
    __shared__ u32 h[512];
    for (int t = tid; t < 512; t += 256) h[t] = 0u;
    __syncthreads();
    int base = b * 8192;
    for (int it = 0; it < 32; it++) {
      int i = base + it * 256 + tid;
      if (i < E) atomicAdd(&h[(u32)dst[i] >> 8], 1u);
    }
    __syncthreads();
    for (int t = tid; t < nbkt; t += 256) {
      u32 c = h[t];
      if (c) atomicAdd(&bktTotal[t], c);
    }
  } else if (b < nba + nbx) {          // x -> xbf (bf16) + xq (fp8 e4m3, natural order)
    int i = (b - nba) * 256 + tid;     // i-th float4
    if (i < N * 32) {
      const float4 v = *(const float4*)(x + (size_t)i * 4);
      ushort4 o = { f2bf(v.x), f2bf(v.y), f2bf(v.z), f2bf(v.w) };
      *(ushort4*)(xbf + (size_t)i * 4) = o;
      u32 p = 0;
      p = __builtin_amdgcn_cvt_pk_fp8_f32(v.x, v.y, p, false);
      p = __builtin_amdgcn_cvt_pk_fp8_f32(v.z, v.w, p, true);
      xq[i] = p;
    }
  } else {                             // W (128 x 256 f32) -> bf16
    int i = (b - nba - nbx) * 256 + tid;
    if (i < 8192) {
      const float4 v = *(const float4*)(W + (size_t)i * 4);
      ushort4 o = { f2bf(v.x), f2bf(v.y), f2bf(v.z), f2bf(v.w) };
      *(ushort4*)(wbf + (size_t)i * 4) = o;
    }
  }
}

// ---------------- bucket scan: starts + cursors + terminal segoff ----------------
__global__ __launch_bounds__(512) void bscan_k(const u32* __restrict__ bktTotal, int nbkt,
                                               int E, u32* __restrict__ start,
                                               u32* __restrict__ cursor,
                                               u32* __restrict__ segoff, int segN) {
  __shared__ u32 s[512];
  int t = threadIdx.x;
  u32 v = (t < nbkt) ? bktTotal[t] : 0u;
  s[t] = v;
  __syncthreads();
  for (int off = 1; off < 512; off <<= 1) {
    u32 x = (t >= off) ? s[t - off] : 0u;
    __syncthreads();
    s[t] += x;
    __syncthreads();
  }
  u32 excl = s[t] - v;
  if (t < nbkt) { start[t] = excl; cursor[t] = excl; }
  if (t == nbkt - 1) start[nbkt] = excl + v;   // == E
  if (t == 0) segoff[segN] = (u32)E;
}

// ---------------- pass A2: partition edges into bucket regions (packed u32) ----------------
__global__ __launch_bounds__(256) void part_k(const int* __restrict__ src, const int* __restrict__ dst,
                                              int E, u32* __restrict__ cursor,
                                              u32* __restrict__ packed, int nbkt) {
  __shared__ u32 h[512];
  for (int t = threadIdx.x; t < 512; t += 256) h[t] = 0u;
  __syncthreads();
  int base = blockIdx.x * 8192;
  for (int it = 0; it < 32; it++) {
    int i = base + it * 256 + threadIdx.x;
    if (i < E) atomicAdd(&h[(u32)dst[i] >> 8], 1u);
  }
  __syncthreads();
  for (int t = threadIdx.x; t < nbkt; t += 256) {
    u32 c = h[t];
    h[t] = c ? atomicAdd(&cursor[t], c) : 0u;   // reserve contiguous per-(block,bucket) range
  }
  __syncthreads();
  for (int it = 0; it < 32; it++) {
    int i = base + it * 256 + threadIdx.x;
    if (i < E) {
      u32 d = (u32)dst[i];
      u32 pos = atomicAdd(&h[d >> 8], 1u);      // LDS atomic (u32 fast path)
      packed[pos] = (u32)src[i] | ((d & 255u) << 24);
    }
  }
}

// ---------------- pass B: per-bucket (node,seg) counting sort -> segoff + ssrc ----------------
// key = local_dst*4 + (src>>15): 1024 keys. segoff[node*4+s] = global start of node's seg-s run.
__global__ __launch_bounds__(256) void bucket_k(const u32* __restrict__ packed,
                                                const u32* __restrict__ start,
                                                u32* __restrict__ segoff, int* __restrict__ ssrc) {
  __shared__ u32 cnt[1024];
  __shared__ u32 cur[1024];
  __shared__ u32 scn[256];
  int b = blockIdx.x, t = threadIdx.x;
  u32 lo = start[b], hi = start[b + 1];
  *(uint4*)&cnt[t * 4] = uint4{0u, 0u, 0u, 0u};
  __syncthreads();
  for (u32 j = lo + t; j < hi; j += 256) {
    u32 w = packed[j];
    u32 key = ((w >> 24) << 2) | ((w & 0xFFFFFFu) >> 15);
    atomicAdd(&cnt[key], 1u);
  }
  __syncthreads();
  u32 c0 = cnt[t*4], c1 = cnt[t*4+1], c2 = cnt[t*4+2], c3 = cnt[t*4+3];
  u32 tot = c0 + c1 + c2 + c3;
  scn[t] = tot;
  __syncthreads();
  for (int off = 1; off < 256; off <<= 1) {
    u32 x = (t >= off) ? scn[t - off] : 0u;
    __syncthreads();
    scn[t] += x;
    __syncthreads();
  }
  u32 p0 = lo + scn[t] - tot;
  u32 p1 = p0 + c0, p2 = p1 + c1, p3 = p2 + c2;
  int node4 = (b * 256 + t) * 4;
  *(uint4*)&segoff[node4] = uint4{p0, p1, p2, p3};
  cur[t*4] = p0; cur[t*4+1] = p1; cur[t*4+2] = p2; cur[t*4+3] = p3;
  __syncthreads();
  for (u32 j = lo + t; j < hi; j += 256) {
    u32 w = packed[j];
    u32 key = ((w >> 24) << 2) | ((w & 0xFFFFFFu) >> 15);
    u32 pos = atomicAdd(&cur[key], 1u);   // LDS atomic (u32)
    ssrc[pos] = (int)(w & 0xFFFFFFu);
  }
}

// ---------------- fused aggregate + GEMM, 4 waves / 64 nodes per block ----------------
// Phase 1: seg-outer (4 src segments of 32K rows = ~4MB, L2-resident chip-wide),
// round-inner: each 16-lane sub-group owns one node per round, 4 rounds' accumulators
// persist in registers across segs. Phase 2: per-wave 16-row MFMA strip.
#define DEC8A(vv, A) { f32x2 p;                                                   \
    p = __builtin_amdgcn_cvt_pk_f32_fp8((vv).x, false); A[0] += p;                \
    p = __builtin_amdgcn_cvt_pk_f32_fp8((vv).x, true);  A[1] += p;                \
    p = __builtin_amdgcn_cvt_pk_f32_fp8((vv).y, false); A[2] += p;                \
    p = __builtin_amdgcn_cvt_pk_f32_fp8((vv).y, true);  A[3] += p; }

__global__ __launch_bounds__(256) void fuse_k(const int* __restrict__ ssrc,
                                              const u32* __restrict__ segoff,
                                              const u32* __restrict__ xq,
                                              const u16* __restrict__ xbf,
                                              const u16* __restrict__ wbf,
                                              const float* __restrict__ bias,
                                              float* __restrict__ out, int N) {
  __shared__ u16 mlds[64][136];               // padded stride vs bank conflicts
  int wv = threadIdx.x >> 6, lane = threadIdx.x & 63;
  int sub = lane >> 4, cl = lane & 15;
  int wbase = blockIdx.x * 64 + wv * 16;      // this wave's 16 nodes / strip rows

  f32x2 acc2[4][4];                           // [round][4 x f32x2] = 32 VGPR... per lane 8 floats/round
#pragma unroll
  for (int r = 0; r < 4; r++)
#pragma unroll
    for (int i = 0; i < 4; i++) acc2[r][i] = f32x2{0.f, 0.f};

#pragma unroll 1
  for (int seg = 0; seg < 4; seg++) {
#pragma unroll
    for (int r = 0; r < 4; r++) {
      int node = wbase + r * 4 + sub;         // < nbkt*256, segoff in-bounds; empty if >= N
      u32 j = segoff[node * 4 + seg];
      u32 j1 = segoff[node * 4 + seg + 1];
      for (; j + 3 < j1; j += 4) {            // 4 rows in flight
        uint4 iA = *(const uint4*)(ssrc + j);
        uint2 v0 = *(const uint2*)(xq + ((size_t)iA.x << 5) + (cl << 1));
        uint2 v1 = *(const uint2*)(xq + ((size_t)iA.y << 5) + (cl << 1));
        uint2 v2 = *(const uint2*)(xq + ((size_t)iA.z << 5) + (cl << 1));
        uint2 v3 = *(const uint2*)(xq + ((size_t)iA.w << 5) + (cl << 1));
        DEC8A(v0, acc2[r]) DEC8A(v1, acc2[r]) DEC8A(v2, acc2[r]) DEC8A(v3, acc2[r])
      }
      for (; j < j1; j++) {
        int e = ssrc[j];
        uint2 v = *(const uint2*)(xq + ((size_t)e << 5) + (cl << 1));
        DEC8A(v, acc2[r])
      }
    }
  }

  // means -> LDS
#pragma unroll
  for (int r = 0; r < 4; r++) {
    int ln = r * 4 + sub;
    int node = wbase + ln;
    u32 deg = segoff[node * 4 + 4] - segoff[node * 4];
    float inv = 1.0f / (float)(deg ? deg : 1u);
    uint4 o;
    o.x = (u32)f2bf(acc2[r][0].x * inv) | ((u32)f2bf(acc2[r][0].y * inv) << 16);
    o.y = (u32)f2bf(acc2[r][1].x * inv) | ((u32)f2bf(acc2[r][1].y * inv) << 16);
    o.z = (u32)f2bf(acc2[r][2].x * inv) | ((u32)f2bf(acc2[r][2].y * inv) << 16);
    o.w = (u32)f2bf(acc2[r][3].x * inv) | ((u32)f2bf(acc2[r][3].y * inv) << 16);
    *(uint4*)&mlds[wv * 16 + ln][cl * 8] = o;   // 16 lanes cover all 128 feats
  }
  __syncthreads();

  // ---- phase 2: 16-row GEMM strip (K=256: x from global, mean from LDS) ----
  int la = cl, lb = sub;
  bf16x8 a[8];
  const u16* ab = xbf + ((size_t)(wbase + la) << 7) + lb * 8;
#pragma unroll
  for (int kb = 0; kb < 4; kb++) a[kb] = *(const bf16x8*)(ab + kb * 32);
#pragma unroll
  for (int kb = 0; kb < 4; kb++) a[4 + kb] = *(const bf16x8*)(&mlds[wv * 16 + la][kb * 32 + lb * 8]);

#pragma unroll
  for (int ct = 0; ct < 8; ct++) {
    f32x4 acc = { 0.f, 0.f, 0.f, 0.f };
    const u16* bbase = wbf + ((size_t)(ct * 16 + la) << 8) + lb * 8;
#pragma unroll
    for (int kb = 0; kb < 8; kb++) {
      bf16x8 b = *(const bf16x8*)(bbase + kb * 32);
      acc = __builtin_amdgcn_mfma_f32_16x16x32_bf16(a[kb], b, acc, 0, 0, 0);
    }
    float bc = bias[ct * 16 + la];
#pragma unroll
    for (int j = 0; j < 4; j++) {
      int r = wbase + lb * 4 + j;
      if (r < N) out[((size_t)r << 7) + ct * 16 + la] = acc[j] + bc;
    }
  }
}

extern "C" void kernel_launch(void* const* d_in, const int* in_sizes, int n_in,
                              void* d_out, int out_size, void* d_ws, size_t ws_size,
                              hipStream_t stream) {
  const float* x    = (const float*)d_in[0];
  const int*   ei   = (const int*)d_in[1];
  const float* W    = (const float*)d_in[2];
  const float* bias = (const float*)d_in[3];
  const int N = in_sizes[0] / 128;
  const int E = in_sizes[1] / 2;
  const int nbkt = (N + 255) >> 8;           // 256-node buckets
  const int segN = nbkt * 256 * 4;           // segoff entries (terminal at [segN])
  const int* src = ei;
  const int* dst = ei + E;
  float* out = (float*)d_out;

  // transient CSR-build scratch in d_out (dead before fuse_k writes out):
  u32* packed   = (u32*)d_out;               // E
  u32* bktTotal = packed + E;                // nbkt
  u32* start    = bktTotal + nbkt;           // nbkt+1
  u32* cursor   = start + nbkt + 1;          // nbkt

  char* ws = (char*)d_ws;
  u32* segoff = (u32*)ws;                    // segN+1
  size_t off = ((size_t)(segN + 1) * 4 + 255) & ~(size_t)255;
  int* ssrc = (int*)(ws + off);              // E
  off += (size_t)E * 4;
  off = (off + 255) & ~(size_t)255;
  u16* xbf = (u16*)(ws + off);               // N*128 bf16
  off += (size_t)N * 128 * 2;
  off = (off + 255) & ~(size_t)255;
  u32* xq = (u32*)(ws + off);                // N*32 u32 (natural-order fp8)
  off += (size_t)N * 128;
  off = (off + 255) & ~(size_t)255;
  u16* wbf = (u16*)(ws + off);               // 128*256 bf16

  const int nbx = (N * 32 + 255) / 256;
  const int nba = (E + 8191) / 8192;
  hipMemsetAsync(bktTotal, 0, (size_t)nbkt * 4, stream);
  pre_k<<<nba + nbx + 32, 256, 0, stream>>>(x, xbf, xq, W, wbf, dst, E, bktTotal, N, nbkt, nba, nbx);
  bscan_k<<<1, 512, 0, stream>>>(bktTotal, nbkt, E, start, cursor, segoff, segN);
  part_k<<<nba, 256, 0, stream>>>(src, dst, E, cursor, packed, nbkt);
  bucket_k<<<nbkt, 256, 0, stream>>>(packed, start, segoff, ssrc);
  fuse_k<<<(N + 63) / 64, 256, 0, stream>>>(ssrc, segoff, xq, xbf, wbf, bias, out, N);
}

// Round 12
// 210.035 us; speedup vs baseline: 1.3479x; 1.3479x over previous
//
#include <hip/hip_runtime.h>

typedef unsigned int u32;
typedef unsigned short u16;
typedef unsigned char u8;
typedef __bf16 bf16x8 __attribute__((ext_vector_type(8)));
typedef float f32x4 __attribute__((ext_vector_type(4)));
typedef float f32x2 __attribute__((ext_vector_type(2)));

__device__ __forceinline__ u16 f2bf(float f) {
  u32 u = __builtin_bit_cast(u32, f);
  u32 r = (u + 0x7fffu + ((u >> 16) & 1u)) >> 16;   // RTNE
  return (u16)r;
}

// ---------------- fused pre-pass: conv x (bf16 + fp8) | zero bktTotal | conv W ----------------
__global__ __launch_bounds__(256) void pre_k(const float* __restrict__ x, u16* __restrict__ xbf,
                                             u32* __restrict__ xq,
                                             const float* __restrict__ W, u16* __restrict__ wbf,
                                             u32* __restrict__ bktTotal, int N, int nbkt,
                                             int nbx, int nbz) {
  int b = blockIdx.x, tid = threadIdx.x;
  if (b < nbx) {                       // x -> xbf (bf16) + xq (fp8 e4m3, natural order, 4/u32)
    int i = b * 256 + tid;             // i-th float4
    if (i < N * 32) {
      const float4 v = *(const float4*)(x + (size_t)i * 4);
      ushort4 o = { f2bf(v.x), f2bf(v.y), f2bf(v.z), f2bf(v.w) };
      *(ushort4*)(xbf + (size_t)i * 4) = o;
      u32 p = 0;
      p = __builtin_amdgcn_cvt_pk_fp8_f32(v.x, v.y, p, false);
      p = __builtin_amdgcn_cvt_pk_fp8_f32(v.z, v.w, p, true);
      xq[i] = p;
    }
  } else if (b < nbx + nbz) {          // zero bucket totals
    int i = (b - nbx) * 256 + tid;
    if (i < nbkt) bktTotal[i] = 0u;
  } else {                             // W (128 x 256 f32) -> bf16
    int i = (b - nbx - nbz) * 256 + tid;
    if (i < 8192) {
      const float4 v = *(const float4*)(W + (size_t)i * 4);
      ushort4 o = { f2bf(v.x), f2bf(v.y), f2bf(v.z), f2bf(v.w) };
      *(ushort4*)(wbf + (size_t)i * 4) = o;
    }
  }
}

// ---------------- pass A1: per-block LDS histogram over buckets (dst>>8) ----------------
__global__ __launch_bounds__(256) void hist_k(const int* __restrict__ dst, int E,
                                              u32* __restrict__ bktTotal, int nbkt) {
  __shared__ u32 h[512];
  for (int t = threadIdx.x; t < 512; t += 256) h[t] = 0u;
  __syncthreads();
  int base = blockIdx.x * 8192;
  for (int it = 0; it < 32; it++) {
    int i = base + it * 256 + threadIdx.x;
    if (i < E) atomicAdd(&h[(u32)dst[i] >> 8], 1u);
  }
  __syncthreads();
  for (int t = threadIdx.x; t < nbkt; t += 256) {
    u32 c = h[t];
    if (c) atomicAdd(&bktTotal[t], c);
  }
}

// ---------------- bucket scan: starts, cursors, offsets[N] ----------------
__global__ __launch_bounds__(512) void bscan_k(const u32* __restrict__ bktTotal, int nbkt,
                                               int E, int N, u32* __restrict__ start,
                                               u32* __restrict__ cursor, u32* __restrict__ offsets) {
  __shared__ u32 s[512];
  int t = threadIdx.x;
  u32 v = (t < nbkt) ? bktTotal[t] : 0u;
  s[t] = v;
  __syncthreads();
  for (int off = 1; off < 512; off <<= 1) {
    u32 x = (t >= off) ? s[t - off] : 0u;
    __syncthreads();
    s[t] += x;
    __syncthreads();
  }
  u32 excl = s[t] - v;
  if (t < nbkt) { start[t] = excl; cursor[t] = excl; }
  if (t == nbkt - 1) start[nbkt] = excl + v;   // == E
  if (t == 0) offsets[N] = (u32)E;
}

// ---------------- pass A2: partition edges into bucket regions (packed u32) ----------------
__global__ __launch_bounds__(256) void part_k(const int* __restrict__ src, const int* __restrict__ dst,
                                              int E, u32* __restrict__ cursor,
                                              u32* __restrict__ packed, int nbkt) {
  __shared__ u32 h[512];
  for (int t = threadIdx.x; t < 512; t += 256) h[t] = 0u;
  __syncthreads();
  int base = blockIdx.x * 8192;
  for (int it = 0; it < 32; it++) {
    int i = base + it * 256 + threadIdx.x;
    if (i < E) atomicAdd(&h[(u32)dst[i] >> 8], 1u);
  }
  __syncthreads();
  for (int t = threadIdx.x; t < nbkt; t += 256) {
    u32 c = h[t];
    h[t] = c ? atomicAdd(&cursor[t], c) : 0u;   // reserve contiguous per-(block,bucket) range
  }
  __syncthreads();
  for (int it = 0; it < 32; it++) {
    int i = base + it * 256 + threadIdx.x;
    if (i < E) {
      u32 d = (u32)dst[i];
      u32 pos = atomicAdd(&h[d >> 8], 1u);      // LDS atomic (u32 fast path)
      packed[pos] = (u32)src[i] | ((d & 255u) << 24);
    }
  }
}

// ---------------- pass B: per-bucket counting sort -> offsets + ssrc + degree-rank perm ----------------
__global__ __launch_bounds__(256) void bucket_k(const u32* __restrict__ packed,
                                                const u32* __restrict__ start, int N,
                                                u32* __restrict__ offsets, int* __restrict__ ssrc,
                                                u8* __restrict__ nodeperm) {
  __shared__ u32 cnt[256];
  __shared__ u32 scn[256];
  __shared__ u32 cur[256];
  int b = blockIdx.x, t = threadIdx.x;
  u32 lo = start[b], hi = start[b + 1];
  cnt[t] = 0u;
  __syncthreads();
  for (u32 j = lo + t; j < hi; j += 256) atomicAdd(&cnt[packed[j] >> 24], 1u);
  __syncthreads();
  u32 v = cnt[t];
  scn[t] = v;
  __syncthreads();
  for (int off = 1; off < 256; off <<= 1) {
    u32 x = (t >= off) ? scn[t - off] : 0u;
    __syncthreads();
    scn[t] += x;
    __syncthreads();
  }
  u32 base = lo + scn[t] - v;     // exclusive position of this node's segment
  int node = b * 256 + t;
  if (node < N) offsets[node] = base;
  cur[t] = base;
  __syncthreads();
  for (u32 j = lo + t; j < hi; j += 256) {
    u32 w = packed[j];
    u32 pos = atomicAdd(&cur[w >> 24], 1u);   // LDS atomic (u32)
    ssrc[pos] = (int)(w & 0xFFFFFFu);
  }
  // degree-rank permutation per 64-node group (ascending degree, stable)
  {
    int g = t >> 6, l = t & 63;
    u32 mykey = cnt[t] * 256u + (u32)l;
    const u32* cg = &cnt[g * 64];
    u32 rank = 0;
#pragma unroll 8
    for (int l2 = 0; l2 < 64; l2++) {
      u32 k2 = cg[l2] * 256u + (u32)l2;
      rank += (k2 < mykey) ? 1u : 0u;
    }
    nodeperm[(size_t)b * 256 + g * 64 + rank] = (u8)l;
  }
}

// ---------------- fused aggregate + GEMM, 4 waves / 64 nodes per block ----------------
// Phase 1: each 16-lane sub-group owns one node per round; round r of all waves covers
// degree-ranks [r*16,(r+1)*16) via nodeperm -> the 4 concurrent nodes per wave have
// near-equal degree (divergence ~0) and waves are quartile-balanced. Next-quad ssrc
// indices are prefetched so the loop chain is row-latency only.
// Phase 2: per-wave 16-row MFMA strip: A = [xbf rows | LDS means], B = wbf.
#define DECV(vv, A0, A1, A2, A3) { f32x2 p;                              \
    p = __builtin_amdgcn_cvt_pk_f32_fp8((vv).x, false); A0 += p;         \
    p = __builtin_amdgcn_cvt_pk_f32_fp8((vv).x, true);  A1 += p;         \
    p = __builtin_amdgcn_cvt_pk_f32_fp8((vv).y, false); A2 += p;         \
    p = __builtin_amdgcn_cvt_pk_f32_fp8((vv).y, true);  A3 += p; }

__global__ __launch_bounds__(256) void fuse_k(const int* __restrict__ ssrc,
                                              const u32* __restrict__ offsets,
                                              const u32* __restrict__ xq,
                                              const u16* __restrict__ xbf,
                                              const u16* __restrict__ wbf,
                                              const float* __restrict__ bias,
                                              const u8* __restrict__ nodeperm,
                                              float* __restrict__ out, int N) {
  __shared__ u16 mlds[64][136];               // padded stride vs bank conflicts
  int wv = threadIdx.x >> 6, lane = threadIdx.x & 63;
  int sub = lane >> 4, cl = lane & 15;
  int nbase = blockIdx.x * 64;

  int pidx[4];
#pragma unroll
  for (int r = 0; r < 4; r++)
    pidx[r] = nodeperm[(size_t)nbase + r * 16 + wv * 4 + sub];

  // ---- phase 1: 4 rounds x 4 concurrent degree-matched nodes per wave ----
  for (int r = 0; r < 4; r++) {
    int ln = pidx[r];
    int node = nbase + ln;
    f32x2 A0{0.f,0.f}, A1{0.f,0.f}, A2{0.f,0.f}, A3{0.f,0.f};
    u32 deg = 0;
    if (node < N) {
      u32 s0 = offsets[node], s1 = offsets[node + 1];
      deg = s1 - s0;
      u32 j = s0;
      u32 nq = deg >> 2;
      if (nq) {
        uint4 iA = *(const uint4*)(ssrc + j);
        for (u32 q = 1; q < nq; q++) {
          uint4 iN = *(const uint4*)(ssrc + j + 4);   // prefetch next quad's indices
          uint2 v0 = *(const uint2*)(xq + ((size_t)iA.x << 5) + (cl << 1));
          uint2 v1 = *(const uint2*)(xq + ((size_t)iA.y << 5) + (cl << 1));
          uint2 v2 = *(const uint2*)(xq + ((size_t)iA.z << 5) + (cl << 1));
          uint2 v3 = *(const uint2*)(xq + ((size_t)iA.w << 5) + (cl << 1));
          DECV(v0, A0, A1, A2, A3) DECV(v1, A0, A1, A2, A3)
          DECV(v2, A0, A1, A2, A3) DECV(v3, A0, A1, A2, A3)
          iA = iN; j += 4;
        }
        {
          uint2 v0 = *(const uint2*)(xq + ((size_t)iA.x << 5) + (cl << 1));
          uint2 v1 = *(const uint2*)(xq + ((size_t)iA.y << 5) + (cl << 1));
          uint2 v2 = *(const uint2*)(xq + ((size_t)iA.z << 5) + (cl << 1));
          uint2 v3 = *(const uint2*)(xq + ((size_t)iA.w << 5) + (cl << 1));
          DECV(v0, A0, A1, A2, A3) DECV(v1, A0, A1, A2, A3)
          DECV(v2, A0, A1, A2, A3) DECV(v3, A0, A1, A2, A3)
          j += 4;
        }
      }
      for (; j < s1; j++) {
        int e = ssrc[j];
        uint2 v = *(const uint2*)(xq + ((size_t)e << 5) + (cl << 1));
        DECV(v, A0, A1, A2, A3)
      }
    }
    float inv = 1.0f / (float)(deg ? deg : 1u);
    uint4 o;
    o.x = (u32)f2bf(A0.x * inv) | ((u32)f2bf(A0.y * inv) << 16);
    o.y = (u32)f2bf(A1.x * inv) | ((u32)f2bf(A1.y * inv) << 16);
    o.z = (u32)f2bf(A2.x * inv) | ((u32)f2bf(A2.y * inv) << 16);
    o.w = (u32)f2bf(A3.x * inv) | ((u32)f2bf(A3.y * inv) << 16);
    *(uint4*)&mlds[ln][cl * 8] = o;           // 16 lanes cover all 128 feats
  }
  __syncthreads();

  // ---- phase 2: 16-row GEMM strip (K=256: x from global, mean from LDS) ----
  int la = cl, lb = sub;
  int wbase = nbase + wv * 16;
  bf16x8 a[8];
  const u16* ab = xbf + ((size_t)(wbase + la) << 7) + lb * 8;
#pragma unroll
  for (int kb = 0; kb < 4; kb++) a[kb] = *(const bf16x8*)(ab + kb * 32);
#pragma unroll
  for (int kb = 0; kb < 4; kb++) a[4 + kb] = *(const bf16x8*)(&mlds[wv * 16 + la][kb * 32 + lb * 8]);

#pragma unroll
  for (int ct = 0; ct < 8; ct++) {
    f32x4 acc = { 0.f, 0.f, 0.f, 0.f };
    const u16* bbase = wbf + ((size_t)(ct * 16 + la) << 8) + lb * 8;
#pragma unroll
    for (int kb = 0; kb < 8; kb++) {
      bf16x8 b = *(const bf16x8*)(bbase + kb * 32);
      acc = __builtin_amdgcn_mfma_f32_16x16x32_bf16(a[kb], b, acc, 0, 0, 0);
    }
    float bc = bias[ct * 16 + la];
#pragma unroll
    for (int j = 0; j < 4; j++) {
      int r = wbase + lb * 4 + j;
      if (r < N) out[((size_t)r << 7) + ct * 16 + la] = acc[j] + bc;
    }
  }
}

extern "C" void kernel_launch(void* const* d_in, const int* in_sizes, int n_in,
                              void* d_out, int out_size, void* d_ws, size_t ws_size,
                              hipStream_t stream) {
  const float* x    = (const float*)d_in[0];
  const int*   ei   = (const int*)d_in[1];
  const float* W    = (const float*)d_in[2];
  const float* bias = (const float*)d_in[3];
  const int N = in_sizes[0] / 128;
  const int E = in_sizes[1] / 2;
  const int nbkt = (N + 255) >> 8;           // 256-node buckets
  const int* src = ei;
  const int* dst = ei + E;
  float* out = (float*)d_out;

  // transient CSR-build scratch in d_out (dead before fuse_k writes out):
  u32* packed   = (u32*)d_out;               // E
  u32* bktTotal = packed + E;                // nbkt
  u32* start    = bktTotal + nbkt;           // nbkt+1
  u32* cursor   = start + nbkt + 1;          // nbkt

  char* ws = (char*)d_ws;
  u32* offsets = (u32*)ws;                   // N+1
  size_t off = ((size_t)(N + 1) * 4 + 255) & ~(size_t)255;
  int* ssrc = (int*)(ws + off);              // E
  off += (size_t)E * 4;
  off = (off + 255) & ~(size_t)255;
  u16* xbf = (u16*)(ws + off);               // N*128 bf16
  off += (size_t)N * 128 * 2;
  off = (off + 255) & ~(size_t)255;
  u32* xq = (u32*)(ws + off);                // N*32 u32 (natural-order fp8)
  off += (size_t)N * 128;
  off = (off + 255) & ~(size_t)255;
  u16* wbf = (u16*)(ws + off);               // 128*256 bf16
  off += (size_t)128 * 256 * 2;
  off = (off + 255) & ~(size_t)255;
  u8* nodeperm = (u8*)(ws + off);            // nbkt*256 bytes

  const int nbx = (N * 32 + 255) / 256;
  const int nbz = (nbkt + 255) / 256;
  const int nba = (E + 8191) / 8192;
  pre_k<<<nbx + nbz + 32, 256, 0, stream>>>(x, xbf, xq, W, wbf, bktTotal, N, nbkt, nbx, nbz);
  hist_k<<<nba, 256, 0, stream>>>(dst, E, bktTotal, nbkt);
  bscan_k<<<1, 512, 0, stream>>>(bktTotal, nbkt, E, N, start, cursor, offsets);
  part_k<<<nba, 256, 0, stream>>>(src, dst, E, cursor, packed, nbkt);
  bucket_k<<<nbkt, 256, 0, stream>>>(packed, start, N, offsets, ssrc, nodeperm);
  fuse_k<<<(N + 63) / 64, 256, 0, stream>>>(ssrc, offsets, xq, xbf, wbf, bias, nodeperm, out, N);
}